// Round 8
// baseline (505.693 us; speedup 1.0000x reference)
//
#include <hip/hip_runtime.h>
#include <math.h>
#include <stdint.h>

#define D 128
#define EPS 1e-6f
typedef unsigned short u16;

// ---------------------------------------------------------------------------
// state layout (floats), 16B-aligned base:
//   st[0..127]   : q
//   st[128..255] : q_plus
//   st[256..383] : hop accumulator (device atomicAdd targets)
//   st[384]      : ||q||   st[385] : ||q_plus||   st[386] : sum-of-exp
// NO device-scope fences anywhere (r6: fences after bulk writes cost ~100us).
// Cross-kernel visibility via stream ordering only.
//
// r8 algorithmic change: key/value rows are never materialized.
//   dot_i = sum_t s[kid_it],  s = T16 @ q_plus      (linearity of the dot)
//   sum_i e_i v_i = sum_v w[v] T16[v],  w[v] = sum_{vid=v} e_i  (scatter)
// Only ||k_i|| needs real row sums -> one key-only gather fused with hop 1.
// ---------------------------------------------------------------------------

__device__ __forceinline__ float wave_sum(float v) {
#pragma unroll
    for (int off = 32; off > 0; off >>= 1) v += __shfl_xor(v, off, 64);
    return v;
}
__device__ __forceinline__ float halfwave_sum(float v) {
#pragma unroll
    for (int off = 16; off > 0; off >>= 1) v += __shfl_xor(v, off, 32);
    return v;
}

__device__ __forceinline__ float bf2f(u16 h) {
    union { unsigned u; float f; } x;
    x.u = ((unsigned)h) << 16;
    return x.f;
}
__device__ __forceinline__ u16 f2bf(float f) {  // round-to-nearest-even
    union { float f; unsigned u; } x;
    x.f = f;
    unsigned u = x.u;
    return (u16)((u + 0x7fff + ((u >> 16) & 1)) >> 16);
}

// ===========================================================================
// K1: fp32 -> bf16 table convert + zero the scatter buffer w.
// ===========================================================================
__global__ void k1_convert(const float4* __restrict__ src,
                           ushort4* __restrict__ dst, int n4,
                           float* __restrict__ w, int VW) {
    int gtid = blockIdx.x * blockDim.x + threadIdx.x;
    int gthreads = gridDim.x * blockDim.x;
    for (int i = gtid; i < n4; i += gthreads) {
        float4 v = src[i];
        ushort4 o;
        o.x = f2bf(v.x); o.y = f2bf(v.y); o.z = f2bf(v.z); o.w = f2bf(v.w);
        dst[i] = o;
    }
    for (int i = gtid; i < VW; i += gthreads) w[i] = 0.f;
}

// ===========================================================================
// Small fp32 encodes: persona rows + q, one block.
// ===========================================================================
__global__ void encode_small(const float* __restrict__ emb,
                             const int* __restrict__ pers, int NP, int LP,
                             const int* __restrict__ xs, int LQ,
                             float* __restrict__ pers_rows,
                             float* __restrict__ pnorms,
                             float* __restrict__ st) {
    int lane = threadIdx.x & 63;
    int w = threadIdx.x >> 6;
    for (int i = w; i <= NP; i += 4) {
        const int* ids;
        int L;
        float* out;
        float* nrm;
        if (i < NP) { ids = pers + (long)i * LP; L = LP; out = pers_rows + (long)i * D; nrm = pnorms + i; }
        else        { ids = xs; L = LQ; out = st; nrm = st + 384; }
        float2 acc = {0.f, 0.f};
        for (int t = 0; t < L; ++t) {
            int idx = ids[t];
            const float2 e = *(const float2*)(emb + (long)idx * D + 2 * lane);
            acc.x += e.x;
            acc.y += e.y;
        }
        *(float2*)(out + 2 * lane) = acc;
        float sq = wave_sum(acc.x * acc.x + acc.y * acc.y);
        if (lane == 0) *nrm = sqrtf(sq);
    }
}

// ===========================================================================
// Hop kernels (1 block, 128 threads) — known-good since r3.
// ===========================================================================
__global__ void persona_hop(const float* __restrict__ pers_rows,
                            const float* __restrict__ pnorms,
                            const float* __restrict__ W,
                            float* __restrict__ st, int NP) {
    __shared__ float qsh[D];
    __shared__ float att[64];
    __shared__ float qh[D];
    __shared__ float red[2];
    int tid = threadIdx.x;
    qsh[tid] = st[tid];
    __syncthreads();
    if (tid < NP) {
        float dot = 0.f;
        for (int d2 = 0; d2 < D; ++d2) dot += pers_rows[tid * D + d2] * qsh[d2];
        att[tid] = dot / fmaxf(pnorms[tid] * st[384], EPS);
    }
    __syncthreads();
    if (tid == 0) {
        float m = -1e30f;
        for (int p = 0; p < NP; ++p) m = fmaxf(m, att[p]);
        float s = 0.f;
        for (int p = 0; p < NP; ++p) { att[p] = __expf(att[p] - m); s += att[p]; }
        float inv = 1.f / s;
        for (int p = 0; p < NP; ++p) att[p] *= inv;
    }
    __syncthreads();
    float h = 0.f;
    for (int p = 0; p < NP; ++p) h += att[p] * pers_rows[p * D + tid];
    qh[tid] = qsh[tid] + h;
    __syncthreads();
    float qp = 0.f;
    for (int d2 = 0; d2 < D; ++d2) qp += W[tid * D + d2] * qh[d2];
    st[128 + tid] = qp;
    float sq = wave_sum(qp * qp);
    if ((tid & 63) == 0) red[tid >> 6] = sq;
    __syncthreads();
    if (tid == 0) st[385] = sqrtf(red[0] + red[1]);
    st[256 + tid] = 0.f;  // zero accumulators for upcoming attention
    if (tid == 0) st[386] = 0.f;
}

__global__ void mid_hop(const float* __restrict__ W1, const float* __restrict__ W2,
                        const float* __restrict__ pers_rows,
                        const float* __restrict__ pnorms,
                        float* __restrict__ st, int NP) {
    __shared__ float qh[D];
    __shared__ float qsh[D];
    __shared__ float att[64];
    __shared__ float red[2];
    int tid = threadIdx.x;
    float inv = 1.f / st[386];
    qh[tid] = st[128 + tid] + st[256 + tid] * inv;
    __syncthreads();
    float qn = 0.f;
    for (int d2 = 0; d2 < D; ++d2) qn += W1[tid * D + d2] * qh[d2];
    qsh[tid] = qn;
    st[tid] = qn;
    float sq = wave_sum(qn * qn);
    if ((tid & 63) == 0) red[tid >> 6] = sq;
    __syncthreads();
    float qnorm = sqrtf(red[0] + red[1]);
    if (tid == 0) st[384] = qnorm;
    if (tid < NP) {
        float dot = 0.f;
        for (int d2 = 0; d2 < D; ++d2) dot += pers_rows[tid * D + d2] * qsh[d2];
        att[tid] = dot / fmaxf(pnorms[tid] * qnorm, EPS);
    }
    __syncthreads();
    if (tid == 0) {
        float m = -1e30f;
        for (int p = 0; p < NP; ++p) m = fmaxf(m, att[p]);
        float s = 0.f;
        for (int p = 0; p < NP; ++p) { att[p] = __expf(att[p] - m); s += att[p]; }
        float is = 1.f / s;
        for (int p = 0; p < NP; ++p) att[p] *= is;
    }
    __syncthreads();
    float h = 0.f;
    for (int p = 0; p < NP; ++p) h += att[p] * pers_rows[p * D + tid];
    qh[tid] = qsh[tid] + h;
    __syncthreads();
    float qp = 0.f;
    for (int d2 = 0; d2 < D; ++d2) qp += W2[tid * D + d2] * qh[d2];
    st[128 + tid] = qp;
    float sq2 = wave_sum(qp * qp);
    if ((tid & 63) == 0) red[tid >> 6] = sq2;
    __syncthreads();
    if (tid == 0) st[385] = sqrtf(red[0] + red[1]);
    st[256 + tid] = 0.f;
    if (tid == 0) st[386] = 0.f;
}

__global__ void finish_hop(const float* __restrict__ W, float* __restrict__ st) {
    __shared__ float qh[D];
    __shared__ float red[2];
    int tid = threadIdx.x;
    float inv = 1.f / st[386];
    qh[tid] = st[128 + tid] + st[256 + tid] * inv;
    __syncthreads();
    float qn = 0.f;
    for (int d2 = 0; d2 < D; ++d2) qn += W[tid * D + d2] * qh[d2];
    st[tid] = qn;
    float sq = wave_sum(qn * qn);
    if ((tid & 63) == 0) red[tid >> 6] = sq;
    __syncthreads();
    if (tid == 0) st[384] = sqrtf(red[0] + red[1]);
}

// ===========================================================================
// B1: key-only gather (bf16 table) fused with attention hop 1.
// 2 rows/wave (half-wave each); computes & stores knorm, dot with q_plus on
// the in-register fp32 row sums, e=exp(cos), scatters e into w via vids,
// block-reduces esum. Value rows never touched.
// ===========================================================================
template <int L>
__global__ void b1_keys_att1(const u16* __restrict__ tbl,
                             const int* __restrict__ kids,
                             const int* __restrict__ vids, int N,
                             float* __restrict__ knorms,
                             float* __restrict__ w,
                             float* __restrict__ st) {
    __shared__ float se[4];
    const int tid = threadIdx.x;
    const int lane = tid & 63;
    const int half = lane >> 5;
    const int hl = lane & 31;
    int gw = (int)((blockIdx.x * blockDim.x + tid) >> 6);
    int nw = (int)((gridDim.x * blockDim.x) >> 6);
    const float4 qp = *(const float4*)(st + 128 + 4 * hl);
    const float qpn = st[385];
    float esum = 0.f;
    const int npair = N >> 1;  // N even
    for (int p = gw; p < npair; p += nw) {
        const int row = 2 * p + half;
        int kid = 0, vid = 0;
        if (hl < L) {
            kid = kids[(long)row * L + hl];
            vid = vids[(long)row * L + hl];
        }
        float4 ka = {0.f, 0.f, 0.f, 0.f};
#pragma unroll
        for (int t = 0; t < L; ++t) {
            const int ki = __shfl(kid, (half << 5) + t, 64);
            const ushort4 ke = *(const ushort4*)(tbl + (long)ki * D + 4 * hl);
            ka.x += bf2f(ke.x); ka.y += bf2f(ke.y);
            ka.z += bf2f(ke.z); ka.w += bf2f(ke.w);
        }
        float nsq = halfwave_sum(ka.x * ka.x + ka.y * ka.y + ka.z * ka.z + ka.w * ka.w);
        float kn = sqrtf(nsq);
        if (hl == 0) knorms[row] = kn;
        float dot = halfwave_sum(ka.x * qp.x + ka.y * qp.y + ka.z * qp.z + ka.w * qp.w);
        const float c = dot / fmaxf(kn * qpn, EPS);
        const float e = __expf(c);  // broadcast across the half-wave
        if (hl < L) atomicAdd(&w[vid], e);
        if (hl == 0) esum += e;
    }
    float et = wave_sum(esum);
    if (lane == 0) se[tid >> 6] = et;
    __syncthreads();
    if (tid == 0) atomicAdd(&st[386], se[0] + se[1] + se[2] + se[3]);
}

// ===========================================================================
// C: hop accumulator = sum_v w[v] * T16[v]  (streams the 12.8 MB table).
// One row per wave, lane owns 2 channels; LDS merge then 128 atomics/block.
// ===========================================================================
__global__ void c_reduce(const u16* __restrict__ tbl, const float* __restrict__ w,
                         float* __restrict__ st, int V) {
    __shared__ float acc_s[128];
    const int tid = threadIdx.x;
    const int lane = tid & 63;
    int gw = (int)((blockIdx.x * blockDim.x + tid) >> 6);
    int nw = (int)((gridDim.x * blockDim.x) >> 6);
    float2 a = {0.f, 0.f};
    for (int v = gw; v < V; v += nw) {
        const float wv = w[v];
        const unsigned u = *(const unsigned*)(tbl + (long)v * D + 2 * lane);
        a.x += wv * bf2f((u16)(u & 0xffff));
        a.y += wv * bf2f((u16)(u >> 16));
    }
    if (tid < 128) acc_s[tid] = 0.f;
    __syncthreads();
    atomicAdd(&acc_s[2 * lane], a.x);
    atomicAdd(&acc_s[2 * lane + 1], a.y);
    __syncthreads();
    if (tid < 128) atomicAdd(&st[256 + tid], acc_s[tid]);
}

// ===========================================================================
// A2: s[v] = T16[v] . q_plus  (stream table once) + re-zero w for hop 2.
// ===========================================================================
__global__ void a2_s(const u16* __restrict__ tbl, const float* __restrict__ st,
                     float* __restrict__ s, int V, float* __restrict__ w, int VW) {
    const int tid = threadIdx.x;
    const int lane = tid & 63;
    int gtid = blockIdx.x * blockDim.x + tid;
    int gthreads = gridDim.x * blockDim.x;
    for (int i = gtid; i < VW; i += gthreads) w[i] = 0.f;
    const float2 qp2 = *(const float2*)(st + 128 + 2 * lane);
    int gw = gtid >> 6;
    int nw = gthreads >> 6;
    for (int v = gw; v < V; v += nw) {
        const unsigned u = *(const unsigned*)(tbl + (long)v * D + 2 * lane);
        float d = bf2f((u16)(u & 0xffff)) * qp2.x + bf2f((u16)(u >> 16)) * qp2.y;
        d = wave_sum(d);
        if (lane == 0) s[v] = d;
    }
}

// ===========================================================================
// B2: hop-2 attention from precomputed s + stored knorms. One row per lane:
// dot = sum_t s[kids], e = exp(cos), scatter e into w, block-reduce esum.
// ===========================================================================
__global__ void b2_mem(const float* __restrict__ s, const int* __restrict__ kids,
                       const int* __restrict__ vids,
                       const float* __restrict__ knorms,
                       float* __restrict__ w, float* __restrict__ st, int N) {
    __shared__ float se[4];
    const int tid = threadIdx.x;
    const int row = blockIdx.x * blockDim.x + tid;
    const float qpn = st[385];
    float e = 0.f;
    if (row < N) {
        const int4* kp = (const int4*)(kids + (long)row * 20);
        int4 k0 = kp[0], k1 = kp[1], k2 = kp[2], k3 = kp[3], k4 = kp[4];
        float dot = s[k0.x] + s[k0.y] + s[k0.z] + s[k0.w] +
                    s[k1.x] + s[k1.y] + s[k1.z] + s[k1.w] +
                    s[k2.x] + s[k2.y] + s[k2.z] + s[k2.w] +
                    s[k3.x] + s[k3.y] + s[k3.z] + s[k3.w] +
                    s[k4.x] + s[k4.y] + s[k4.z] + s[k4.w];
        const float c = dot / fmaxf(knorms[row] * qpn, EPS);
        e = __expf(c);
        const int4* vp = (const int4*)(vids + (long)row * 20);
#pragma unroll
        for (int j = 0; j < 5; ++j) {
            int4 v4 = vp[j];
            atomicAdd(&w[v4.x], e);
            atomicAdd(&w[v4.y], e);
            atomicAdd(&w[v4.z], e);
            atomicAdd(&w[v4.w], e);
        }
    }
    float et = wave_sum(e);
    if ((tid & 63) == 0) se[tid >> 6] = et;
    __syncthreads();
    if (tid == 0) atomicAdd(&st[386], se[0] + se[1] + se[2] + se[3]);
}

// ===========================================================================
// K5: candidate gather + cosine, fused (fp32 cemb, never materialized).
// ===========================================================================
__global__ void k5_final(const float* __restrict__ cemb,
                         const int* __restrict__ cands, int NC,
                         const float* __restrict__ st, float* __restrict__ out) {
    const int lane = threadIdx.x & 63;
    const int half = lane >> 5;
    const int hl = lane & 31;
    const int gw = (int)((blockIdx.x * blockDim.x + threadIdx.x) >> 6);
    const int nw = (int)((gridDim.x * blockDim.x) >> 6);
    const float4 q4 = *(const float4*)(st + 4 * hl);
    const float qn = st[384];
    const int npair = (NC + 1) >> 1;
    for (int p = gw; p < npair; p += nw) {
        const int row = 2 * p + half;
        const bool valid = row < NC;
        const int rowc = valid ? row : (NC - 1);
        int myid = 0;
        if (hl < 20) myid = cands[(long)rowc * 20 + hl];
        float4 acc = {0.f, 0.f, 0.f, 0.f};
#pragma unroll
        for (int t = 0; t < 20; ++t) {
            const int idx = __shfl(myid, (half << 5) + t, 64);
            const float4 e = *(const float4*)(cemb + (long)idx * D + 4 * hl);
            acc.x += e.x; acc.y += e.y; acc.z += e.z; acc.w += e.w;
        }
        float dot = halfwave_sum(acc.x * q4.x + acc.y * q4.y +
                                 acc.z * q4.z + acc.w * q4.w);
        float nsq = halfwave_sum(acc.x * acc.x + acc.y * acc.y +
                                 acc.z * acc.z + acc.w * acc.w);
        if (valid && hl == 0) out[row] = dot / fmaxf(sqrtf(nsq) * qn, EPS);
    }
}

// ===========================================================================
// Fallback big attention: fp32 on-the-fly gather (workspace too small).
// ===========================================================================
__global__ void big_att_rc(const float* __restrict__ emb,
                           const int* __restrict__ kids,
                           const int* __restrict__ vids,
                           float* __restrict__ st, int N) {
    __shared__ float s[129];
    const int tid = threadIdx.x;
    const int lane = tid & 63;
    const int half = lane >> 5;
    const int hl = lane & 31;
    const int gw = (int)((blockIdx.x * blockDim.x + tid) >> 6);
    const int nw = (int)((gridDim.x * blockDim.x) >> 6);
    const float4 qp = *(const float4*)(st + 128 + 4 * hl);
    const float qpn = st[385];
    float4 hacc = {0.f, 0.f, 0.f, 0.f};
    float esum = 0.f;
    const int npair = (N + 1) >> 1;
    for (int p = gw; p < npair; p += nw) {
        const int row = 2 * p + half;
        const bool valid = row < N;
        const int rowc = valid ? row : (N - 1);
        int kid = 0, vid = 0;
        if (hl < 20) {
            kid = kids[(long)rowc * 20 + hl];
            vid = vids[(long)rowc * 20 + hl];
        }
        float4 ka = {0.f, 0.f, 0.f, 0.f}, va = {0.f, 0.f, 0.f, 0.f};
#pragma unroll
        for (int t = 0; t < 20; ++t) {
            const int ki = __shfl(kid, (half << 5) + t, 64);
            const int vi = __shfl(vid, (half << 5) + t, 64);
            const float4 ke = *(const float4*)(emb + (long)ki * D + 4 * hl);
            const float4 ve = *(const float4*)(emb + (long)vi * D + 4 * hl);
            ka.x += ke.x; ka.y += ke.y; ka.z += ke.z; ka.w += ke.w;
            va.x += ve.x; va.y += ve.y; va.z += ve.z; va.w += ve.w;
        }
        float nsq = halfwave_sum(ka.x * ka.x + ka.y * ka.y + ka.z * ka.z + ka.w * ka.w);
        float dot = halfwave_sum(ka.x * qp.x + ka.y * qp.y + ka.z * qp.z + ka.w * qp.w);
        const float c = dot / fmaxf(sqrtf(nsq) * qpn, EPS);
        float e = __expf(c);
        if (!valid) e = 0.f;
        hacc.x += e * va.x; hacc.y += e * va.y;
        hacc.z += e * va.z; hacc.w += e * va.w;
        if (hl == 0) esum += e;
    }
    hacc.x += __shfl_xor(hacc.x, 32, 64);
    hacc.y += __shfl_xor(hacc.y, 32, 64);
    hacc.z += __shfl_xor(hacc.z, 32, 64);
    hacc.w += __shfl_xor(hacc.w, 32, 64);
    esum += __shfl_xor(esum, 32, 64);
    if (tid < 129) s[tid] = 0.f;
    __syncthreads();
    if (half == 0) {
        atomicAdd(&s[4 * hl + 0], hacc.x);
        atomicAdd(&s[4 * hl + 1], hacc.y);
        atomicAdd(&s[4 * hl + 2], hacc.z);
        atomicAdd(&s[4 * hl + 3], hacc.w);
        if (hl == 0) atomicAdd(&s[128], esum);
    }
    __syncthreads();
    if (tid < 128) atomicAdd(&st[256 + tid], s[tid]);
    if (tid == 128) atomicAdd(&st[386], s[128]);
}

static inline size_t align16(size_t b) { return (b + 15) & ~(size_t)15; }

extern "C" void kernel_launch(void* const* d_in, const int* in_sizes, int n_in,
                              void* d_out, int out_size, void* d_ws, size_t ws_size,
                              hipStream_t stream) {
    const int* xs = (const int*)d_in[0];
    const int* cands = (const int*)d_in[1];
    const int* pers = (const int*)d_in[2];
    const int* keys = (const int*)d_in[3];
    const int* values = (const int*)d_in[4];
    const float* semb = (const float*)d_in[6];
    const float* cemb = (const float*)d_in[7];
    const float* RW = (const float*)d_in[8];
    const float* R2W = (const float*)d_in[9];
    float* out = (float*)d_out;

    const int L = 20;
    const int LQ = in_sizes[0];
    const int VD = in_sizes[6];         // V*D
    const int V = VD / D;               // 50000
    const int NMEM = in_sizes[3] / L;   // 65536
    const int NCAND = in_sizes[1] / L;  // 10000
    const int NPERS = in_sizes[2] / L;  // 20

    size_t need = align16((size_t)VD * 2) + align16((size_t)NMEM * 4) +
                  align16((size_t)V * 4) * 2 + align16((size_t)NPERS * D * 4) +
                  align16((size_t)NPERS * 4) + 512 * 4;
    bool stored = (d_ws != nullptr) && (ws_size >= need) && (NMEM % 2 == 0) &&
                  ((VD & 3) == 0) && (NMEM % 256 == 0);

    const int THR = 256;
    char* base = (char*)d_ws;
    u16* tbl16 = nullptr;
    float *knorms = nullptr, *sv = nullptr, *wv = nullptr;
    if (stored) {
        tbl16 = (u16*)base;   base += align16((size_t)VD * 2);
        knorms = (float*)base; base += align16((size_t)NMEM * 4);
        sv = (float*)base;     base += align16((size_t)V * 4);
        wv = (float*)base;     base += align16((size_t)V * 4);
    }
    float* enc_pers = (float*)base; base += align16((size_t)NPERS * D * 4);
    float* pnorms = (float*)base;   base += align16((size_t)NPERS * 4);
    float* st = (float*)base;

    if (stored) {
        // K1: convert table to bf16 + zero w
        int n4 = VD / 4;
        k1_convert<<<(n4 + THR - 1) / THR, THR, 0, stream>>>(
            (const float4*)semb, (ushort4*)tbl16, n4, wv, V);
        // small encodes + persona hop 1 (zeroes acc/esum)
        encode_small<<<1, THR, 0, stream>>>(semb, pers, NPERS, L, xs, LQ,
                                            enc_pers, pnorms, st);
        persona_hop<<<1, 128, 0, stream>>>(enc_pers, pnorms, RW, st, NPERS);
        // B1: key gather + att hop 1 (stores knorms, scatters w, esum)
        {
            int npair = NMEM / 2;
            int blocks = (npair + 3) / 4;  // 1 pair/wave, full oversubscription
            b1_keys_att1<20><<<blocks, THR, 0, stream>>>(tbl16, keys, values,
                                                         NMEM, knorms, wv, st);
        }
        // C1: acc = sum_v w[v] T16[v]
        c_reduce<<<1024, THR, 0, stream>>>(tbl16, wv, st, V);
        // mid-hop (consumes acc/esum, zeroes them, produces q_plus2)
        mid_hop<<<1, 128, 0, stream>>>(RW, R2W, enc_pers, pnorms, st, NPERS);
        // A2: s = T16 @ q_plus2, re-zero w
        {
            int blocks = (V + 3) / 4;  // 1 row/wave
            if (blocks > 12544) blocks = 12544;
            a2_s<<<blocks, THR, 0, stream>>>(tbl16, st, sv, V, wv, V);
        }
        // B2: dots from s + stored knorms; scatter w; esum
        b2_mem<<<NMEM / THR, THR, 0, stream>>>(sv, keys, values, knorms, wv, st,
                                               NMEM);
        // C2
        c_reduce<<<1024, THR, 0, stream>>>(tbl16, wv, st, V);
        finish_hop<<<1, 128, 0, stream>>>(R2W, st);
        // K5: fused candidate gather + cosine
        int nblk5 = (((NCAND + 1) / 2) + 3) / 4;
        k5_final<<<nblk5, THR, 0, stream>>>(cemb, cands, NCAND, st, out);
        (void)n_in; (void)out_size;
        return;
    }

    // -------- fallback: fp32 on-the-fly gather --------
    encode_small<<<1, THR, 0, stream>>>(semb, pers, NPERS, L, xs, LQ,
                                        enc_pers, pnorms, st);
    persona_hop<<<1, 128, 0, stream>>>(enc_pers, pnorms, RW, st, NPERS);
    big_att_rc<<<1024, THR, 0, stream>>>(semb, keys, values, st, NMEM);
    mid_hop<<<1, 128, 0, stream>>>(RW, R2W, enc_pers, pnorms, st, NPERS);
    big_att_rc<<<1024, THR, 0, stream>>>(semb, keys, values, st, NMEM);
    finish_hop<<<1, 128, 0, stream>>>(R2W, st);
    int nblk5 = (((NCAND + 1) / 2) + 3) / 4;
    k5_final<<<nblk5, THR, 0, stream>>>(cemb, cands, NCAND, st, out);

    (void)n_in; (void)out_size;
}

// Round 9
// 394.468 us; speedup vs baseline: 1.2820x; 1.2820x over previous
//
#include <hip/hip_runtime.h>
#include <math.h>
#include <stdint.h>

#define D 128
#define EPS 1e-6f
typedef unsigned short u16;

// ---------------------------------------------------------------------------
// state layout (floats), 16B-aligned base:
//   st[0..127]   : q
//   st[128..255] : q_plus
//   st[256..383] : hop accumulator (device atomicAdd targets)
//   st[384]      : ||q||   st[385] : ||q_plus||   st[386] : sum-of-exp
// No device-scope fences (r6: ~100us L2-writeback cost). No global atomic
// scatters on big arrays (r8: ~84ns/atomic under contention).
// ---------------------------------------------------------------------------

__device__ __forceinline__ float wave_sum(float v) {
#pragma unroll
    for (int off = 32; off > 0; off >>= 1) v += __shfl_xor(v, off, 64);
    return v;
}
__device__ __forceinline__ float halfwave_sum(float v) {
#pragma unroll
    for (int off = 16; off > 0; off >>= 1) v += __shfl_xor(v, off, 32);
    return v;
}
__device__ __forceinline__ float quarter_sum(float v) {
#pragma unroll
    for (int off = 8; off > 0; off >>= 1) v += __shfl_xor(v, off, 16);
    return v;
}

__device__ __forceinline__ float bf2f(u16 h) {
    union { unsigned u; float f; } x;
    x.u = ((unsigned)h) << 16;
    return x.f;
}
__device__ __forceinline__ float bflo(unsigned u) { return bf2f((u16)(u & 0xffff)); }
__device__ __forceinline__ float bfhi(unsigned u) { return bf2f((u16)(u >> 16)); }
__device__ __forceinline__ u16 f2bf(float f) {  // round-to-nearest-even
    union { float f; unsigned u; } x;
    x.f = f;
    unsigned u = x.u;
    return (u16)((u + 0x7fff + ((u >> 16) & 1)) >> 16);
}
__device__ __forceinline__ unsigned pack2(float a, float b) {
    return (unsigned)f2bf(a) | ((unsigned)f2bf(b) << 16);
}

// ===========================================================================
// K1: streaming fp32 -> bf16 table conversion.
// ===========================================================================
__global__ void table_to_bf16(const float4* __restrict__ src,
                              ushort4* __restrict__ dst, int n4) {
    int i = blockIdx.x * blockDim.x + threadIdx.x;
    if (i < n4) {
        float4 v = src[i];
        ushort4 o;
        o.x = f2bf(v.x); o.y = f2bf(v.y); o.z = f2bf(v.z); o.w = f2bf(v.w);
        dst[i] = o;
    }
}

// ===========================================================================
// K2 (r9 A/B): fused k+v gather, 4 rows/wave. Quarter-wave (16 lanes) owns a
// row; lane loads uint4 = 16B = 8 bf16 channels. Per wave-iteration: 40 vmem
// instrs fetching 8 row-gathers (1KB/instr) — half the instruction count of
// the r7 2-row/ushort4 version at identical total line traffic.
// ===========================================================================
template <int L>  // L == 20
__global__ void encode_kv4(const u16* __restrict__ tbl,
                           const int* __restrict__ kids,
                           const int* __restrict__ vids, int N,
                           u16* __restrict__ krows, u16* __restrict__ vrows,
                           float* __restrict__ knorms) {
    const int lane = threadIdx.x & 63;
    const int q = lane >> 4;   // quarter 0..3 (row within group)
    const int ql = lane & 15;  // lane within quarter: channels 8*ql..8*ql+7
    int gw = (int)((blockIdx.x * blockDim.x + threadIdx.x) >> 6);
    int nw = (int)((gridDim.x * blockDim.x) >> 6);
    const int nquad = N >> 2;  // N % 4 == 0 guaranteed by caller
    for (int g = gw; g < nquad; g += nw) {
        const long ibase = (long)g * (4 * L);  // 4 rows' ids, contiguous
        // preload all 80 k-ids and 80 v-ids into 2 regs each
        int kidA = kids[ibase + lane];
        int vidA = vids[ibase + lane];
        int kidB = (lane < 4 * L - 64) ? kids[ibase + 64 + lane] : 0;
        int vidB = (lane < 4 * L - 64) ? vids[ibase + 64 + lane] : 0;
        float ka[8], va[8];
#pragma unroll
        for (int c = 0; c < 8; ++c) { ka[c] = 0.f; va[c] = 0.f; }
#pragma unroll
        for (int t = 0; t < L; ++t) {
            const int j = L * q + t;  // source slot for this quarter's token t
            const int jb = j - 64;
            int kA = __shfl(kidA, j & 63, 64);
            int kB = __shfl(kidB, jb < 0 ? 0 : jb, 64);
            int vA = __shfl(vidA, j & 63, 64);
            int vB = __shfl(vidB, jb < 0 ? 0 : jb, 64);
            const int kj = (j < 64) ? kA : kB;
            const int vj = (j < 64) ? vA : vB;
            const uint4 ke = *(const uint4*)(tbl + (long)kj * D + 8 * ql);
            const uint4 ve = *(const uint4*)(tbl + (long)vj * D + 8 * ql);
            ka[0] += bflo(ke.x); ka[1] += bfhi(ke.x);
            ka[2] += bflo(ke.y); ka[3] += bfhi(ke.y);
            ka[4] += bflo(ke.z); ka[5] += bfhi(ke.z);
            ka[6] += bflo(ke.w); ka[7] += bfhi(ke.w);
            va[0] += bflo(ve.x); va[1] += bfhi(ve.x);
            va[2] += bflo(ve.y); va[3] += bfhi(ve.y);
            va[4] += bflo(ve.z); va[5] += bfhi(ve.z);
            va[6] += bflo(ve.w); va[7] += bfhi(ve.w);
        }
        const int row = 4 * g + q;
        uint4 ko, vo;
        ko.x = pack2(ka[0], ka[1]); ko.y = pack2(ka[2], ka[3]);
        ko.z = pack2(ka[4], ka[5]); ko.w = pack2(ka[6], ka[7]);
        vo.x = pack2(va[0], va[1]); vo.y = pack2(va[2], va[3]);
        vo.z = pack2(va[4], va[5]); vo.w = pack2(va[6], va[7]);
        *(uint4*)(krows + (long)row * D + 8 * ql) = ko;
        *(uint4*)(vrows + (long)row * D + 8 * ql) = vo;
        float nsq = 0.f;
#pragma unroll
        for (int c = 0; c < 8; ++c) nsq += ka[c] * ka[c];
        nsq = quarter_sum(nsq);
        if (ql == 0) knorms[row] = sqrtf(nsq);
    }
}

// ===========================================================================
// Small fp32 encodes: persona rows + q, one block.
// ===========================================================================
__global__ void encode_small(const float* __restrict__ emb,
                             const int* __restrict__ pers, int NP, int LP,
                             const int* __restrict__ xs, int LQ,
                             float* __restrict__ pers_rows,
                             float* __restrict__ pnorms,
                             float* __restrict__ st) {
    int lane = threadIdx.x & 63;
    int w = threadIdx.x >> 6;
    for (int i = w; i <= NP; i += 4) {
        const int* ids;
        int L;
        float* out;
        float* nrm;
        if (i < NP) { ids = pers + (long)i * LP; L = LP; out = pers_rows + (long)i * D; nrm = pnorms + i; }
        else        { ids = xs; L = LQ; out = st; nrm = st + 384; }
        float2 acc = {0.f, 0.f};
        for (int t = 0; t < L; ++t) {
            int idx = ids[t];
            const float2 e = *(const float2*)(emb + (long)idx * D + 2 * lane);
            acc.x += e.x;
            acc.y += e.y;
        }
        *(float2*)(out + 2 * lane) = acc;
        float sq = wave_sum(acc.x * acc.x + acc.y * acc.y);
        if (lane == 0) *nrm = sqrtf(sq);
    }
}

// ===========================================================================
// Hop kernels (1 block, 128 threads) — known-good since r3.
// ===========================================================================
__global__ void persona_hop(const float* __restrict__ pers_rows,
                            const float* __restrict__ pnorms,
                            const float* __restrict__ W,
                            float* __restrict__ st, int NP) {
    __shared__ float qsh[D];
    __shared__ float att[64];
    __shared__ float qh[D];
    __shared__ float red[2];
    int tid = threadIdx.x;
    qsh[tid] = st[tid];
    __syncthreads();
    if (tid < NP) {
        float dot = 0.f;
        for (int d2 = 0; d2 < D; ++d2) dot += pers_rows[tid * D + d2] * qsh[d2];
        att[tid] = dot / fmaxf(pnorms[tid] * st[384], EPS);
    }
    __syncthreads();
    if (tid == 0) {
        float m = -1e30f;
        for (int p = 0; p < NP; ++p) m = fmaxf(m, att[p]);
        float s = 0.f;
        for (int p = 0; p < NP; ++p) { att[p] = __expf(att[p] - m); s += att[p]; }
        float inv = 1.f / s;
        for (int p = 0; p < NP; ++p) att[p] *= inv;
    }
    __syncthreads();
    float h = 0.f;
    for (int p = 0; p < NP; ++p) h += att[p] * pers_rows[p * D + tid];
    qh[tid] = qsh[tid] + h;
    __syncthreads();
    float qp = 0.f;
    for (int d2 = 0; d2 < D; ++d2) qp += W[tid * D + d2] * qh[d2];
    st[128 + tid] = qp;
    float sq = wave_sum(qp * qp);
    if ((tid & 63) == 0) red[tid >> 6] = sq;
    __syncthreads();
    if (tid == 0) st[385] = sqrtf(red[0] + red[1]);
    st[256 + tid] = 0.f;  // zero accumulators for upcoming attention
    if (tid == 0) st[386] = 0.f;
}

__global__ void mid_hop(const float* __restrict__ W1, const float* __restrict__ W2,
                        const float* __restrict__ pers_rows,
                        const float* __restrict__ pnorms,
                        float* __restrict__ st, int NP) {
    __shared__ float qh[D];
    __shared__ float qsh[D];
    __shared__ float att[64];
    __shared__ float red[2];
    int tid = threadIdx.x;
    float inv = 1.f / st[386];
    qh[tid] = st[128 + tid] + st[256 + tid] * inv;
    __syncthreads();
    float qn = 0.f;
    for (int d2 = 0; d2 < D; ++d2) qn += W1[tid * D + d2] * qh[d2];
    qsh[tid] = qn;
    st[tid] = qn;
    float sq = wave_sum(qn * qn);
    if ((tid & 63) == 0) red[tid >> 6] = sq;
    __syncthreads();
    float qnorm = sqrtf(red[0] + red[1]);
    if (tid == 0) st[384] = qnorm;
    if (tid < NP) {
        float dot = 0.f;
        for (int d2 = 0; d2 < D; ++d2) dot += pers_rows[tid * D + d2] * qsh[d2];
        att[tid] = dot / fmaxf(pnorms[tid] * qnorm, EPS);
    }
    __syncthreads();
    if (tid == 0) {
        float m = -1e30f;
        for (int p = 0; p < NP; ++p) m = fmaxf(m, att[p]);
        float s = 0.f;
        for (int p = 0; p < NP; ++p) { att[p] = __expf(att[p] - m); s += att[p]; }
        float is = 1.f / s;
        for (int p = 0; p < NP; ++p) att[p] *= is;
    }
    __syncthreads();
    float h = 0.f;
    for (int p = 0; p < NP; ++p) h += att[p] * pers_rows[p * D + tid];
    qh[tid] = qsh[tid] + h;
    __syncthreads();
    float qp = 0.f;
    for (int d2 = 0; d2 < D; ++d2) qp += W2[tid * D + d2] * qh[d2];
    st[128 + tid] = qp;
    float sq2 = wave_sum(qp * qp);
    if ((tid & 63) == 0) red[tid >> 6] = sq2;
    __syncthreads();
    if (tid == 0) st[385] = sqrtf(red[0] + red[1]);
    st[256 + tid] = 0.f;
    if (tid == 0) st[386] = 0.f;
}

__global__ void finish_hop(const float* __restrict__ W, float* __restrict__ st) {
    __shared__ float qh[D];
    __shared__ float red[2];
    int tid = threadIdx.x;
    float inv = 1.f / st[386];
    qh[tid] = st[128 + tid] + st[256 + tid] * inv;
    __syncthreads();
    float qn = 0.f;
    for (int d2 = 0; d2 < D; ++d2) qn += W[tid * D + d2] * qh[d2];
    st[tid] = qn;
    float sq = wave_sum(qn * qn);
    if ((tid & 63) == 0) red[tid >> 6] = sq;
    __syncthreads();
    if (tid == 0) st[384] = sqrtf(red[0] + red[1]);
}

// ===========================================================================
// Big attention over stored bf16 rows (1024 blocks). r3 known-good.
// ===========================================================================
__global__ void big_att_bf16(const u16* __restrict__ krows,
                             const float* __restrict__ knorms,
                             const u16* __restrict__ vrows,
                             float* __restrict__ st, int N) {
    __shared__ float s[129];
    int tid = threadIdx.x;
    int lane = tid & 63;
    int half = lane >> 5, hl = lane & 31;
    int gw = (int)((blockIdx.x * blockDim.x + tid) >> 6);
    int nw = (int)((gridDim.x * blockDim.x) >> 6);
    const float4 qp = *(const float4*)(st + 128 + 4 * hl);
    const float qpn = st[385];
    float4 acc = {0.f, 0.f, 0.f, 0.f};
    float esum = 0.f;
    const int npair = N >> 1;
    for (int p = gw; p < npair; p += nw) {
        const int i = 2 * p + half;
        const ushort4 kh = *(const ushort4*)(krows + (long)i * D + 4 * hl);
        float dot = bf2f(kh.x) * qp.x + bf2f(kh.y) * qp.y +
                    bf2f(kh.z) * qp.z + bf2f(kh.w) * qp.w;
        dot = halfwave_sum(dot);
        const float c = dot / fmaxf(knorms[i] * qpn, EPS);
        const float e = __expf(c);
        const ushort4 vh = *(const ushort4*)(vrows + (long)i * D + 4 * hl);
        acc.x += e * bf2f(vh.x);
        acc.y += e * bf2f(vh.y);
        acc.z += e * bf2f(vh.z);
        acc.w += e * bf2f(vh.w);
        if (hl == 0) esum += e;
    }
    acc.x += __shfl_xor(acc.x, 32, 64);
    acc.y += __shfl_xor(acc.y, 32, 64);
    acc.z += __shfl_xor(acc.z, 32, 64);
    acc.w += __shfl_xor(acc.w, 32, 64);
    esum += __shfl_xor(esum, 32, 64);
    if (tid < 129) s[tid] = 0.f;
    __syncthreads();
    if (half == 0) {
        atomicAdd(&s[4 * hl + 0], acc.x);
        atomicAdd(&s[4 * hl + 1], acc.y);
        atomicAdd(&s[4 * hl + 2], acc.z);
        atomicAdd(&s[4 * hl + 3], acc.w);
        if (hl == 0) atomicAdd(&s[128], esum);
    }
    __syncthreads();
    if (tid < 128) atomicAdd(&st[256 + tid], s[tid]);
    if (tid == 128) atomicAdd(&st[386], s[128]);
}

// ===========================================================================
// K5: candidate gather + cosine, fused (enc_cands never materialized).
// ===========================================================================
__global__ void k5_final(const float* __restrict__ cemb,
                         const int* __restrict__ cands, int NC,
                         const float* __restrict__ st, float* __restrict__ out) {
    const int lane = threadIdx.x & 63;
    const int half = lane >> 5;
    const int hl = lane & 31;
    const int gw = (int)((blockIdx.x * blockDim.x + threadIdx.x) >> 6);
    const int nw = (int)((gridDim.x * blockDim.x) >> 6);
    const float4 q4 = *(const float4*)(st + 4 * hl);
    const float qn = st[384];
    const int npair = (NC + 1) >> 1;
    for (int p = gw; p < npair; p += nw) {
        const int row = 2 * p + half;
        const bool valid = row < NC;
        const int rowc = valid ? row : (NC - 1);
        int myid = 0;
        if (hl < 20) myid = cands[(long)rowc * 20 + hl];
        float4 acc = {0.f, 0.f, 0.f, 0.f};
#pragma unroll
        for (int t = 0; t < 20; ++t) {
            const int idx = __shfl(myid, (half << 5) + t, 64);
            const float4 e = *(const float4*)(cemb + (long)idx * D + 4 * hl);
            acc.x += e.x; acc.y += e.y; acc.z += e.z; acc.w += e.w;
        }
        float dot = halfwave_sum(acc.x * q4.x + acc.y * q4.y +
                                 acc.z * q4.z + acc.w * q4.w);
        float nsq = halfwave_sum(acc.x * acc.x + acc.y * acc.y +
                                 acc.z * acc.z + acc.w * acc.w);
        if (valid && hl == 0) out[row] = dot / fmaxf(sqrtf(nsq) * qn, EPS);
    }
}

// ===========================================================================
// Fallback big attention: fp32 on-the-fly gather (workspace too small).
// ===========================================================================
__global__ void big_att_rc(const float* __restrict__ emb,
                           const int* __restrict__ kids,
                           const int* __restrict__ vids,
                           float* __restrict__ st, int N) {
    __shared__ float s[129];
    const int tid = threadIdx.x;
    const int lane = tid & 63;
    const int half = lane >> 5;
    const int hl = lane & 31;
    const int gw = (int)((blockIdx.x * blockDim.x + tid) >> 6);
    const int nw = (int)((gridDim.x * blockDim.x) >> 6);
    const float4 qp = *(const float4*)(st + 128 + 4 * hl);
    const float qpn = st[385];
    float4 hacc = {0.f, 0.f, 0.f, 0.f};
    float esum = 0.f;
    const int npair = (N + 1) >> 1;
    for (int p = gw; p < npair; p += nw) {
        const int row = 2 * p + half;
        const bool valid = row < N;
        const int rowc = valid ? row : (N - 1);
        int kid = 0, vid = 0;
        if (hl < 20) {
            kid = kids[(long)rowc * 20 + hl];
            vid = vids[(long)rowc * 20 + hl];
        }
        float4 ka = {0.f, 0.f, 0.f, 0.f}, va = {0.f, 0.f, 0.f, 0.f};
#pragma unroll
        for (int t = 0; t < 20; ++t) {
            const int ki = __shfl(kid, (half << 5) + t, 64);
            const int vi = __shfl(vid, (half << 5) + t, 64);
            const float4 ke = *(const float4*)(emb + (long)ki * D + 4 * hl);
            const float4 ve = *(const float4*)(emb + (long)vi * D + 4 * hl);
            ka.x += ke.x; ka.y += ke.y; ka.z += ke.z; ka.w += ke.w;
            va.x += ve.x; va.y += ve.y; va.z += ve.z; va.w += ve.w;
        }
        float nsq = halfwave_sum(ka.x * ka.x + ka.y * ka.y + ka.z * ka.z + ka.w * ka.w);
        float dot = halfwave_sum(ka.x * qp.x + ka.y * qp.y + ka.z * qp.z + ka.w * qp.w);
        const float c = dot / fmaxf(sqrtf(nsq) * qpn, EPS);
        float e = __expf(c);
        if (!valid) e = 0.f;
        hacc.x += e * va.x; hacc.y += e * va.y;
        hacc.z += e * va.z; hacc.w += e * va.w;
        if (hl == 0) esum += e;
    }
    hacc.x += __shfl_xor(hacc.x, 32, 64);
    hacc.y += __shfl_xor(hacc.y, 32, 64);
    hacc.z += __shfl_xor(hacc.z, 32, 64);
    hacc.w += __shfl_xor(hacc.w, 32, 64);
    esum += __shfl_xor(esum, 32, 64);
    if (tid < 129) s[tid] = 0.f;
    __syncthreads();
    if (half == 0) {
        atomicAdd(&s[4 * hl + 0], hacc.x);
        atomicAdd(&s[4 * hl + 1], hacc.y);
        atomicAdd(&s[4 * hl + 2], hacc.z);
        atomicAdd(&s[4 * hl + 3], hacc.w);
        if (hl == 0) atomicAdd(&s[128], esum);
    }
    __syncthreads();
    if (tid < 128) atomicAdd(&st[256 + tid], s[tid]);
    if (tid == 128) atomicAdd(&st[386], s[128]);
}

static inline size_t align16(size_t b) { return (b + 15) & ~(size_t)15; }

extern "C" void kernel_launch(void* const* d_in, const int* in_sizes, int n_in,
                              void* d_out, int out_size, void* d_ws, size_t ws_size,
                              hipStream_t stream) {
    const int* xs = (const int*)d_in[0];
    const int* cands = (const int*)d_in[1];
    const int* pers = (const int*)d_in[2];
    const int* keys = (const int*)d_in[3];
    const int* values = (const int*)d_in[4];
    const float* semb = (const float*)d_in[6];
    const float* cemb = (const float*)d_in[7];
    const float* RW = (const float*)d_in[8];
    const float* R2W = (const float*)d_in[9];
    float* out = (float*)d_out;

    const int L = 20;
    const int LQ = in_sizes[0];
    const int VD = in_sizes[6];         // V*D
    const int NMEM = in_sizes[3] / L;   // 65536
    const int NCAND = in_sizes[1] / L;  // 10000
    const int NPERS = in_sizes[2] / L;  // 20

    size_t need = align16((size_t)VD * 2) + 2 * align16((size_t)NMEM * D * 2) +
                  align16((size_t)NMEM * 4) + align16((size_t)NPERS * D * 4) +
                  align16((size_t)NPERS * 4) + 512 * 4;
    bool stored = (d_ws != nullptr) && (ws_size >= need) && (NMEM % 4 == 0) &&
                  ((VD & 3) == 0);

    const int THR = 256;
    char* base = (char*)d_ws;
    u16 *tbl16 = nullptr, *kb = nullptr, *vb = nullptr;
    float* knorms = nullptr;
    if (stored) {
        tbl16 = (u16*)base;  base += align16((size_t)VD * 2);
        kb = (u16*)base;     base += align16((size_t)NMEM * D * 2);
        vb = (u16*)base;     base += align16((size_t)NMEM * D * 2);
        knorms = (float*)base; base += align16((size_t)NMEM * 4);
    }
    float* enc_pers = (float*)base; base += align16((size_t)NPERS * D * 4);
    float* pnorms = (float*)base;   base += align16((size_t)NPERS * 4);
    float* st = (float*)base;

    if (stored) {
        // K1: table convert
        int n4 = VD / 4;
        table_to_bf16<<<(n4 + THR - 1) / THR, THR, 0, stream>>>(
            (const float4*)semb, (ushort4*)tbl16, n4);
        // K2: fused kv gather, 4 rows/wave, uint4 (16B/lane) loads
        {
            int nquad = NMEM / 4;          // waves needed (1 quad per wave)
            int blocks = (nquad + 3) / 4;  // 4 waves/block
            encode_kv4<20><<<blocks, THR, 0, stream>>>(tbl16, keys, values,
                                                       NMEM, kb, vb, knorms);
        }
        // small encodes + hop 1 front-end
        encode_small<<<1, THR, 0, stream>>>(semb, pers, NPERS, L, xs, LQ,
                                            enc_pers, pnorms, st);
        persona_hop<<<1, 128, 0, stream>>>(enc_pers, pnorms, RW, st, NPERS);
        // attention hop 1
        big_att_bf16<<<1024, THR, 0, stream>>>(kb, knorms, vb, st, NMEM);
        mid_hop<<<1, 128, 0, stream>>>(RW, R2W, enc_pers, pnorms, st, NPERS);
        // attention hop 2
        big_att_bf16<<<1024, THR, 0, stream>>>(kb, knorms, vb, st, NMEM);
        finish_hop<<<1, 128, 0, stream>>>(R2W, st);
        // final: fused candidate gather + cosine
        int nblk5 = (((NCAND + 1) / 2) + 3) / 4;
        k5_final<<<nblk5, THR, 0, stream>>>(cemb, cands, NCAND, st, out);
        (void)n_in; (void)out_size;
        return;
    }

    // -------- fallback: fp32 on-the-fly gather --------
    encode_small<<<1, THR, 0, stream>>>(semb, pers, NPERS, L, xs, LQ,
                                        enc_pers, pnorms, st);
    persona_hop<<<1, 128, 0, stream>>>(enc_pers, pnorms, RW, st, NPERS);
    big_att_rc<<<1024, THR, 0, stream>>>(semb, keys, values, st, NMEM);
    mid_hop<<<1, 128, 0, stream>>>(RW, R2W, enc_pers, pnorms, st, NPERS);
    big_att_rc<<<1024, THR, 0, stream>>>(semb, keys, values, st, NMEM);
    finish_hop<<<1, 128, 0, stream>>>(R2W, st);
    int nblk5 = (((NCAND + 1) / 2) + 3) / 4;
    k5_final<<<nblk5, THR, 0, stream>>>(cemb, cands, NCAND, st, out);

    (void)n_in; (void)out_size;
}